// Round 20
// baseline (62.961 us; speedup 1.0000x reference)
//
#include <hip/hip_runtime.h>
#include <math.h>

#define HID 128
#define BQ 65536
#define NPIX_LR 524288
#define OW 512
#define NPIX_HR 2097152
#define OUT_OFF_DX 6291456
#define OUT_OFF_VAR 6291472

// ws layout (bytes) — A2/A1/A3 contiguous (45056 B, staged to LDS in kernel A);
// VA1/VA2H contiguous (12288 B, staged to LDS in kernel B)
#define WS_A2    0        // 32768 : w2^T K32-frags (32 tiles: T = t2*4+kt), sigma-packed
#define WS_A1    32768    // 8192  : w1^T (+b1) K32-frags (8 m-tiles, split in k-slots)
#define WS_A3    40960    // 4096  : w3^T K32-frags (4 k-tiles), sigma-packed
#define WS_VA1   45056    // 8192  : vw1^T (+vb1) K32-frags (8 m-tiles, hi-only in k0..3)
#define WS_VA2H  53248    // 4096  : vw2^T K32-frags (4 k-tiles), sigma-packed
#define WS_LR    57344    // 6291456 : low-res SoA f32

typedef __fp16   hf2   __attribute__((ext_vector_type(2)));
typedef _Float16 f16x8 __attribute__((ext_vector_type(8)));
typedef float    f32x4 __attribute__((ext_vector_type(4)));

static __device__ inline unsigned pack_f16pair(float a, float b) {
    hf2 h; h[0] = (__fp16)a; h[1] = (__fp16)b;
    return __builtin_bit_cast(unsigned, h);
}
static __device__ inline float f16lo(float v) { return v - (float)(__fp16)v; }

// cvt two f32 -> packed f16 (RTZ) then relu via packed f16 max
static __device__ inline unsigned cvt_relu(float a, float b) {
    hf2 h = __builtin_amdgcn_cvt_pkrtz(a, b);
    unsigned u = __builtin_bit_cast(unsigned, h);
    unsigned zero = 0u, d;
    asm("v_pk_max_f16 %0, %1, %2" : "=v"(d) : "v"(u), "v"(zero));
    return d;
}

// ---------------- Prep ----------------
// sigma: k-slot for frag elem (kt, g, j) = (2kt + (j>=4))*16 + g*4 + (j&3)
__device__ inline int sigma(int kt, int g, int j) {
    return (2 * kt + (j >> 2)) * 16 + g * 4 + (j & 3);
}

__device__ inline float a1v32(int g, int j, int m, const float* w1, const float* b1) {
    if (g != 0) return 0.f;
    switch (j) {
    case 0: return w1[m];
    case 1: return w1[HID + m];
    case 2: return w1[m];
    case 3: return w1[HID + m];
    case 4: return f16lo(w1[m]);
    case 5: return f16lo(w1[HID + m]);
    case 6: return b1[m];
    case 7: return f16lo(b1[m]);
    }
    return 0.f;
}

__device__ inline float va1v32(int g, int j, int m, const float* vw1, const float* vb1) {
    if (g != 0 || j >= 4) return 0.f;
    if (j < 3) return vw1[j * HID + m];
    return vb1[m];
}

__global__ void inr_prep(const float* __restrict__ w1, const float* __restrict__ b1,
                         const float* __restrict__ w2, const float* __restrict__ w3,
                         const float* __restrict__ vw1, const float* __restrict__ vb1,
                         const float* __restrict__ vw2, char* ws)
{
    int tid = blockIdx.x * 256 + threadIdx.x;
    if (tid < 8192) {                      // A2: 32 tiles (t2*4+kt)
        int d = tid & 3, l = (tid >> 2) & 63, T = tid >> 8;
        int g = l >> 4, li = l & 15, t2 = T >> 2, kt = T & 3;
        int col = 16 * t2 + li;
        int s0 = sigma(kt, g, 2 * d), s1 = sigma(kt, g, 2 * d + 1);
        ((unsigned*)(ws + WS_A2))[tid] = pack_f16pair(w2[s0 * HID + col], w2[s1 * HID + col]);
    } else if (tid < 10240) {              // A1: 8 m-tiles
        int q = tid - 8192;
        int d = q & 3, l = (q >> 2) & 63, t = q >> 8;
        int g = l >> 4, li = l & 15, m = 16 * t + li;
        ((unsigned*)(ws + WS_A1))[q] = pack_f16pair(a1v32(g, 2 * d, m, w1, b1),
                                                    a1v32(g, 2 * d + 1, m, w1, b1));
    } else if (tid < 11264) {              // A3: 4 k-tiles
        int q = tid - 10240;
        int d = q & 3, l = (q >> 2) & 63, kt = q >> 8;
        int g = l >> 4, li = l & 15;
        int s0 = sigma(kt, g, 2 * d), s1 = sigma(kt, g, 2 * d + 1);
        float v0 = (li < 3) ? w3[s0 * 3 + li] : 0.f;
        float v1 = (li < 3) ? w3[s1 * 3 + li] : 0.f;
        ((unsigned*)(ws + WS_A3))[q] = pack_f16pair(v0, v1);
    } else if (tid < 13312) {              // VA1: 8 m-tiles (hi-only)
        int q = tid - 11264;
        int d = q & 3, l = (q >> 2) & 63, t = q >> 8;
        int g = l >> 4, li = l & 15, m = 16 * t + li;
        ((unsigned*)(ws + WS_VA1))[q] = pack_f16pair(va1v32(g, 2 * d, m, vw1, vb1),
                                                     va1v32(g, 2 * d + 1, m, vw1, vb1));
    } else if (tid < 14336) {              // VA2H: 4 k-tiles
        int q = tid - 13312;
        int d = q & 3, l = (q >> 2) & 63, kt = q >> 8;
        int g = l >> 4, li = l & 15;
        int s0 = sigma(kt, g, 2 * d), s1 = sigma(kt, g, 2 * d + 1);
        float v0 = (li < 3) ? vw2[s0 * 3 + li] : 0.f;
        float v1 = (li < 3) ? vw2[s1 * 3 + li] : 0.f;
        ((unsigned*)(ws + WS_VA2H))[q] = pack_f16pair(v0, v1);
    }
}

// ---------------- Kernel A: K32-MFMA MLP, LDS frags, 32 px/wave-iter (2 B-sets per ds_read) ----------------
#define A_ITERS 4
__global__ __launch_bounds__(256, 2) void inr_mlp_mfma(
    const float* __restrict__ x, const int* __restrict__ sidx,
    const float* __restrict__ shv, const float* __restrict__ rot,
    const float* __restrict__ cw, const float* __restrict__ cb,
    const float* __restrict__ b2g, const float* __restrict__ b3g,
    const char* __restrict__ ws, float* __restrict__ lr)
{
    __shared__ uint4 sFrag[2816];   // 45056 B: A2 [0..2047], A1 [2048..2559], A3 [2560..2815]
    int tid = threadIdx.x, l = tid & 63, wv = tid >> 6;
    int li = l & 15, g = l >> 4;

    {
        const uint4* wsf = (const uint4*)ws;
        #pragma unroll
        for (int i = 0; i < 11; i++) sFrag[i * 256 + tid] = wsf[i * 256 + tid];
    }

    int base = blockIdx.x * (128 * A_ITERS);   // 512 px per block
    int img = base >> 16;
    int si = sidx[img];
    float ang = rot[si], sn, cs;
    sincosf(ang, &sn, &cs);
    float shx = shv[2*si], shy = shv[2*si+1];
    bool aff = (si != 0);
    float cw0 = cw[si*3+0], cw1 = cw[si*3+1], cw2 = cw[si*3+2];
    float cb0 = cb[si*3+0], cb1 = cb[si*3+1], cb2 = cb[si*3+2];
    float b30 = b3g[0], b31 = b3g[1], b32 = b3g[2];
    const unsigned ONES = 0x3C003C00u;  // (1.0h, 1.0h)

    __syncthreads();
    const uint4* fp = sFrag + l;    // per-lane frag base; tile i at fp[i*64]

    int pidxA = base + wv * 32 + li;       // set A pixel for this lane's li
    float2 xvA = ((const float2*)x)[pidxA];
    float2 xvB = ((const float2*)x)[pidxA + 16];

    #pragma unroll 1
    for (int it = 0; it < A_ITERS; ++it) {
        float2 xvAn, xvBn;
        if (it < A_ITERS - 1) {
            xvAn = ((const float2*)x)[pidxA + (it + 1) * 128];
            xvBn = ((const float2*)x)[pidxA + 16 + (it + 1) * 128];
        }
        int p0w = base + it * 128 + wv * 32;

        // build B1 frags for both pixel sets
        f16x8 B1A, B1B;
        {
            float cx = fmaf(cs, xvA.x, fmaf(-sn, xvA.y, shx));
            float cy = fmaf(sn, xvA.x, fmaf(cs, xvA.y, shy));
            hf2 ph = __builtin_amdgcn_cvt_pkrtz(cx, cy);
            hf2 pl = __builtin_amdgcn_cvt_pkrtz(cx - (float)ph[0], cy - (float)ph[1]);
            unsigned uh = __builtin_bit_cast(unsigned, ph);
            unsigned ul = __builtin_bit_cast(unsigned, pl);
            uint4 u; u.x = (g == 0) ? uh : 0u; u.y = (g == 0) ? ul : 0u;
            u.z = (g == 0) ? uh : 0u; u.w = (g == 0) ? ONES : 0u;
            B1A = __builtin_bit_cast(f16x8, u);
        }
        {
            float cx = fmaf(cs, xvB.x, fmaf(-sn, xvB.y, shx));
            float cy = fmaf(sn, xvB.x, fmaf(cs, xvB.y, shy));
            hf2 ph = __builtin_amdgcn_cvt_pkrtz(cx, cy);
            hf2 pl = __builtin_amdgcn_cvt_pkrtz(cx - (float)ph[0], cy - (float)ph[1]);
            unsigned uh = __builtin_bit_cast(unsigned, ph);
            unsigned ul = __builtin_bit_cast(unsigned, pl);
            uint4 u; u.x = (g == 0) ? uh : 0u; u.y = (g == 0) ? ul : 0u;
            u.z = (g == 0) ? uh : 0u; u.w = (g == 0) ? ONES : 0u;
            B1B = __builtin_bit_cast(f16x8, u);
        }

        // layer 1: 8 tile-reads, 2 MFMAs each
        uint2 C1A[8], C1B[8];
        #pragma unroll
        for (int t = 0; t < 8; t++) {
            f16x8 a1 = __builtin_bit_cast(f16x8, fp[2048 + t * 64]);
            f32x4 hA = __builtin_amdgcn_mfma_f32_16x16x32_f16(a1, B1A, (f32x4){0.f,0.f,0.f,0.f}, 0, 0, 0);
            f32x4 hB = __builtin_amdgcn_mfma_f32_16x16x32_f16(a1, B1B, (f32x4){0.f,0.f,0.f,0.f}, 0, 0, 0);
            C1A[t].x = cvt_relu(hA[0], hA[1]); C1A[t].y = cvt_relu(hA[2], hA[3]);
            C1B[t].x = cvt_relu(hB[0], hB[1]); C1B[t].y = cvt_relu(hB[2], hB[3]);
        }

        // layer 2: 32 tile-reads, 2 MFMAs each
        uint2 C2A[8], C2B[8];
        #pragma unroll
        for (int t2 = 0; t2 < 8; t2++) {
            f32x4 cA = *(const f32x4*)(b2g + 16 * t2 + g * 4);
            f32x4 cB = cA;
            #pragma unroll
            for (int kt = 0; kt < 4; kt++) {
                f16x8 a2 = __builtin_bit_cast(f16x8, fp[(t2 * 4 + kt) * 64]);
                uint4 buA = {C1A[2*kt].x, C1A[2*kt].y, C1A[2*kt+1].x, C1A[2*kt+1].y};
                uint4 buB = {C1B[2*kt].x, C1B[2*kt].y, C1B[2*kt+1].x, C1B[2*kt+1].y};
                cA = __builtin_amdgcn_mfma_f32_16x16x32_f16(a2, __builtin_bit_cast(f16x8, buA), cA, 0, 0, 0);
                cB = __builtin_amdgcn_mfma_f32_16x16x32_f16(a2, __builtin_bit_cast(f16x8, buB), cB, 0, 0, 0);
            }
            C2A[t2].x = cvt_relu(cA[0], cA[1]); C2A[t2].y = cvt_relu(cA[2], cA[3]);
            C2B[t2].x = cvt_relu(cB[0], cB[1]); C2B[t2].y = cvt_relu(cB[2], cB[3]);
        }

        // layer 3: 4 tile-reads, 2 MFMAs each (single chain per set)
        f32x4 aA = {0.f,0.f,0.f,0.f}, aB = {0.f,0.f,0.f,0.f};
        #pragma unroll
        for (int kt = 0; kt < 4; kt++) {
            f16x8 a3 = __builtin_bit_cast(f16x8, fp[2560 + kt * 64]);
            uint4 buA = {C2A[(2*kt)&7].x, C2A[(2*kt)&7].y, C2A[(2*kt+1)&7].x, C2A[(2*kt+1)&7].y};
            uint4 buB = {C2B[(2*kt)&7].x, C2B[(2*kt)&7].y, C2B[(2*kt+1)&7].x, C2B[(2*kt+1)&7].y};
            aA = __builtin_amdgcn_mfma_f32_16x16x32_f16(a3, __builtin_bit_cast(f16x8, buA), aA, 0, 0, 0);
            aB = __builtin_amdgcn_mfma_f32_16x16x32_f16(a3, __builtin_bit_cast(f16x8, buB), aB, 0, 0, 0);
        }

        if (g == 0) {   // rows 0..2 = channels, col = px = li
            float vA0 = aA[0] + b30, vA1 = aA[1] + b31, vA2 = aA[2] + b32;
            float vB0 = aB[0] + b30, vB1 = aB[1] + b31, vB2 = aB[2] + b32;
            if (aff) {
                vA0 = fmaf(vA0, cw0, cb0); vA1 = fmaf(vA1, cw1, cb1); vA2 = fmaf(vA2, cw2, cb2);
                vB0 = fmaf(vB0, cw0, cb0); vB1 = fmaf(vB1, cw1, cb1); vB2 = fmaf(vB2, cw2, cb2);
            }
            lr[p0w + li] = vA0;               lr[p0w + 16 + li] = vB0;
            lr[NPIX_LR + p0w + li] = vA1;     lr[NPIX_LR + p0w + 16 + li] = vB1;
            lr[2 * NPIX_LR + p0w + li] = vA2; lr[2 * NPIX_LR + p0w + 16 + li] = vB2;
        }
        xvA = xvAn; xvB = xvBn;
    }
}

// ---------------- Kernel B: reg frags + tap prefetch (r18 body + r13 pipeline) ----------------
#define B_ITERS 4

struct Taps {
    float2 a0, a1, a2;   // row y0: ch0..2, cols (xa, xa+1)
    float2 b0, b1, b2;   // row y1
    float w00, w01, w10, w11;
};

static __device__ inline Taps issue_taps(const float* __restrict__ lr, int px) {
    Taps t;
    int b = px >> 18, r = px & 262143;
    int oy = r >> 9, ox = r & 511;
    int my = oy >> 1, mx = ox >> 1;
    int y0 = (oy & 1) ? my : my - 1;
    int x0 = (ox & 1) ? mx : mx - 1;
    float wy0 = (oy & 1) ? 0.75f : 0.25f;
    float wx0 = (ox & 1) ? 0.75f : 0.25f;
    int y0c = max(y0, 0), y1c = min(y0 + 1, 255);
    int xa = min(max(x0, 0), 254);
    float wxa = (x0 < 0) ? 1.f : ((x0 > 254) ? 0.f : wx0);
    float wxb = (x0 < 0) ? 0.f : ((x0 > 254) ? 1.f : 1.f - wx0);
    float wy1 = 1.f - wy0;
    t.w00 = wy0 * wxa; t.w01 = wy0 * wxb;
    t.w10 = wy1 * wxa; t.w11 = wy1 * wxb;
    int base = b << 16;
    int o0 = base + y0c * 256 + xa;
    int o1 = base + y1c * 256 + xa;
    t.a0 = *(const float2*)(lr + o0);
    t.a1 = *(const float2*)(lr + NPIX_LR + o0);
    t.a2 = *(const float2*)(lr + 2 * NPIX_LR + o0);
    t.b0 = *(const float2*)(lr + o1);
    t.b1 = *(const float2*)(lr + NPIX_LR + o1);
    t.b2 = *(const float2*)(lr + 2 * NPIX_LR + o1);
    return t;
}

__global__ __launch_bounds__(256, 4) void inr_upsample_var(
    const float* __restrict__ lr, const int* __restrict__ sidx,
    const float* __restrict__ shv, const float* __restrict__ vb2g,
    const char* __restrict__ ws, float* __restrict__ out)
{
    __shared__ uint4 sV[768];   // 12288 B: VA1 [0..511], VA2H [512..767]
    int tid = threadIdx.x, l = tid & 63, wv = tid >> 6;
    int li = l & 15, g = l >> 4;

    {
        const uint4* wsv = (const uint4*)(ws + WS_VA1);
        #pragma unroll
        for (int i = 0; i < 3; i++) sV[i * 256 + tid] = wsv[i * 256 + tid];
    }
    float vb20 = vb2g[0], vb21 = vb2g[1], vb22 = vb2g[2];
    __syncthreads();

    // hoist block-invariant weight frags LDS -> registers (12 x 16B = 48 VGPR)
    f16x8 F1[8], F2[4];
    {
        const uint4* vp = sV + l;
        #pragma unroll
        for (int t = 0; t < 8; t++) F1[t] = __builtin_bit_cast(f16x8, vp[t * 64]);
        #pragma unroll
        for (int t = 0; t < 4; t++) F2[t] = __builtin_bit_cast(f16x8, vp[512 + t * 64]);
    }

    int wbase = (blockIdx.x * 4 + wv) * (64 * B_ITERS);
    Taps tp = issue_taps(lr, wbase + l);   // prefetch iter 0

    #pragma unroll 1
    for (int it = 0; it < B_ITERS; ++it) {
        Taps tn;
        if (it + 1 < B_ITERS) tn = issue_taps(lr, wbase + (it + 1) * 64 + l);
        int pxb = wbase + it * 64;
        int px = pxb + l;

        float o0 = tp.w00 * tp.a0.x + tp.w01 * tp.a0.y + tp.w10 * tp.b0.x + tp.w11 * tp.b0.y;
        float o1 = tp.w00 * tp.a1.x + tp.w01 * tp.a1.y + tp.w10 * tp.b1.x + tp.w11 * tp.b1.y;
        float o2 = tp.w00 * tp.a2.x + tp.w01 * tp.a2.y + tp.w10 * tp.b2.x + tp.w11 * tp.b2.y;

        {
            float* dst = out + (size_t)px * 3;
            dst[0] = o0; dst[1] = o1; dst[2] = o2;
        }

        // pack P to f16 on the OWNING lane, shfl the packed dwords
        unsigned u1 = pack_f16pair(o0, o1);
        unsigned u2 = pack_f16pair(o2, 1.0f);

        #pragma unroll
        for (int j = 0; j < 4; j++) {
            int srcl = j * 16 + li;
            unsigned sA = (unsigned)__shfl((int)u1, srcl, 64);
            unsigned sB = (unsigned)__shfl((int)u2, srcl, 64);
            uint4 b1u;
            b1u.x = (g == 0) ? sA : 0u;
            b1u.y = (g == 0) ? sB : 0u;
            b1u.z = 0u;
            b1u.w = 0u;
            f16x8 B1 = __builtin_bit_cast(f16x8, b1u);

            // v1: 8 x K32 MFMA (frags in regs), cvt+relu(f16)
            uint2 C1[8];
            #pragma unroll
            for (int t = 0; t < 8; t++) {
                f32x4 vh = __builtin_amdgcn_mfma_f32_16x16x32_f16(F1[t], B1, (f32x4){0.f,0.f,0.f,0.f}, 0, 0, 0);
                C1[t].x = cvt_relu(vh[0], vh[1]);
                C1[t].y = cvt_relu(vh[2], vh[3]);
            }

            // v2: 4 x K32 MFMA (frags in regs)
            f32x4 acc = {0.f, 0.f, 0.f, 0.f};
            #pragma unroll
            for (int kt = 0; kt < 4; kt++) {
                uint4 bu = {C1[2*kt].x, C1[2*kt].y, C1[2*kt+1].x, C1[2*kt+1].y};
                acc = __builtin_amdgcn_mfma_f32_16x16x32_f16(F2[kt],
                        __builtin_bit_cast(f16x8, bu), acc, 0, 0, 0);
            }

            if (g == 0) {   // rows 0..2 = channels, col = px = li
                float* var = out + OUT_OFF_VAR + (size_t)(pxb + j * 16 + li) * 3;
                var[0] = __expf(acc[0] + vb20);
                var[1] = __expf(acc[1] + vb21);
                var[2] = __expf(acc[2] + vb22);
            }
        }
        tp = tn;
    }

    if (blockIdx.x == 0 && tid < 16) {
        out[OUT_OFF_DX + tid] = shv[2 * sidx[tid & 7] + (tid >> 3)];
    }
}

extern "C" void kernel_launch(void* const* d_in, const int* in_sizes, int n_in,
                              void* d_out, int out_size, void* d_ws, size_t ws_size,
                              hipStream_t stream)
{
    const float* x    = (const float*)d_in[0];
    const int*   sidx = (const int*)d_in[1];
    const float* shv  = (const float*)d_in[3];
    const float* rot  = (const float*)d_in[4];
    const float* cwp  = (const float*)d_in[5];
    const float* cbp  = (const float*)d_in[6];
    const float* w1   = (const float*)d_in[7];
    const float* b1   = (const float*)d_in[8];
    const float* w2   = (const float*)d_in[9];
    const float* b2   = (const float*)d_in[10];
    const float* w3   = (const float*)d_in[11];
    const float* b3   = (const float*)d_in[12];
    const float* vw1  = (const float*)d_in[13];
    const float* vb1  = (const float*)d_in[14];
    const float* vw2  = (const float*)d_in[15];
    const float* vb2  = (const float*)d_in[16];

    char* ws = (char*)d_ws;
    float* lr = (float*)(ws + WS_LR);

    inr_prep<<<56, 256, 0, stream>>>(w1, b1, w2, w3, vw1, vb1, vw2, ws);
    inr_mlp_mfma<<<NPIX_LR / (128 * A_ITERS), 256, 0, stream>>>(x, sidx, shv, rot, cwp, cbp, b2, b3, ws, lr);
    inr_upsample_var<<<NPIX_HR / (256 * B_ITERS), 256, 0, stream>>>(lr, sidx, shv, vb2, ws, (float*)d_out);
}

// Round 21
// 59.720 us; speedup vs baseline: 1.0543x; 1.0543x over previous
//
#include <hip/hip_runtime.h>
#include <math.h>

#define HID 128
#define BQ 65536
#define NPIX_LR 524288
#define OW 512
#define NPIX_HR 2097152
#define OUT_OFF_DX 6291456
#define OUT_OFF_VAR 6291472

// ws layout (bytes) — A2/A1/A3 contiguous (45056 B, staged to LDS in kernel A);
// VA1/VA2H contiguous (12288 B, staged to LDS in kernel B)
#define WS_A2    0        // 32768 : w2^T K32-frags (32 tiles: T = t2*4+kt), sigma-packed
#define WS_A1    32768    // 8192  : w1^T (+b1) K32-frags (8 m-tiles, split in k-slots)
#define WS_A3    40960    // 4096  : w3^T K32-frags (4 k-tiles), sigma-packed
#define WS_VA1   45056    // 8192  : vw1^T (+vb1) K32-frags (8 m-tiles, hi-only in k0..3)
#define WS_VA2H  53248    // 4096  : vw2^T K32-frags (4 k-tiles), sigma-packed
#define WS_LR    57344    // 6291456 : low-res SoA f32

typedef __fp16   hf2   __attribute__((ext_vector_type(2)));
typedef _Float16 f16x8 __attribute__((ext_vector_type(8)));
typedef float    f32x4 __attribute__((ext_vector_type(4)));

static __device__ inline unsigned pack_f16pair(float a, float b) {
    hf2 h; h[0] = (__fp16)a; h[1] = (__fp16)b;
    return __builtin_bit_cast(unsigned, h);
}
static __device__ inline float f16lo(float v) { return v - (float)(__fp16)v; }

// cvt two f32 -> packed f16 (RTZ) then relu via packed f16 max
static __device__ inline unsigned cvt_relu(float a, float b) {
    hf2 h = __builtin_amdgcn_cvt_pkrtz(a, b);
    unsigned u = __builtin_bit_cast(unsigned, h);
    unsigned zero = 0u, d;
    asm("v_pk_max_f16 %0, %1, %2" : "=v"(d) : "v"(u), "v"(zero));
    return d;
}

// ---------------- Prep ----------------
// sigma: k-slot for frag elem (kt, g, j) = (2kt + (j>=4))*16 + g*4 + (j&3)
__device__ inline int sigma(int kt, int g, int j) {
    return (2 * kt + (j >> 2)) * 16 + g * 4 + (j & 3);
}

__device__ inline float a1v32(int g, int j, int m, const float* w1, const float* b1) {
    if (g != 0) return 0.f;
    switch (j) {
    case 0: return w1[m];
    case 1: return w1[HID + m];
    case 2: return w1[m];
    case 3: return w1[HID + m];
    case 4: return f16lo(w1[m]);
    case 5: return f16lo(w1[HID + m]);
    case 6: return b1[m];
    case 7: return f16lo(b1[m]);
    }
    return 0.f;
}

__device__ inline float va1v32(int g, int j, int m, const float* vw1, const float* vb1) {
    if (g != 0 || j >= 4) return 0.f;
    if (j < 3) return vw1[j * HID + m];
    return vb1[m];
}

__global__ void inr_prep(const float* __restrict__ w1, const float* __restrict__ b1,
                         const float* __restrict__ w2, const float* __restrict__ w3,
                         const float* __restrict__ vw1, const float* __restrict__ vb1,
                         const float* __restrict__ vw2, char* ws)
{
    int tid = blockIdx.x * 256 + threadIdx.x;
    if (tid < 8192) {                      // A2: 32 tiles (t2*4+kt)
        int d = tid & 3, l = (tid >> 2) & 63, T = tid >> 8;
        int g = l >> 4, li = l & 15, t2 = T >> 2, kt = T & 3;
        int col = 16 * t2 + li;
        int s0 = sigma(kt, g, 2 * d), s1 = sigma(kt, g, 2 * d + 1);
        ((unsigned*)(ws + WS_A2))[tid] = pack_f16pair(w2[s0 * HID + col], w2[s1 * HID + col]);
    } else if (tid < 10240) {              // A1: 8 m-tiles
        int q = tid - 8192;
        int d = q & 3, l = (q >> 2) & 63, t = q >> 8;
        int g = l >> 4, li = l & 15, m = 16 * t + li;
        ((unsigned*)(ws + WS_A1))[q] = pack_f16pair(a1v32(g, 2 * d, m, w1, b1),
                                                    a1v32(g, 2 * d + 1, m, w1, b1));
    } else if (tid < 11264) {              // A3: 4 k-tiles
        int q = tid - 10240;
        int d = q & 3, l = (q >> 2) & 63, kt = q >> 8;
        int g = l >> 4, li = l & 15;
        int s0 = sigma(kt, g, 2 * d), s1 = sigma(kt, g, 2 * d + 1);
        float v0 = (li < 3) ? w3[s0 * 3 + li] : 0.f;
        float v1 = (li < 3) ? w3[s1 * 3 + li] : 0.f;
        ((unsigned*)(ws + WS_A3))[q] = pack_f16pair(v0, v1);
    } else if (tid < 13312) {              // VA1: 8 m-tiles (hi-only)
        int q = tid - 11264;
        int d = q & 3, l = (q >> 2) & 63, t = q >> 8;
        int g = l >> 4, li = l & 15, m = 16 * t + li;
        ((unsigned*)(ws + WS_VA1))[q] = pack_f16pair(va1v32(g, 2 * d, m, vw1, vb1),
                                                     va1v32(g, 2 * d + 1, m, vw1, vb1));
    } else if (tid < 14336) {              // VA2H: 4 k-tiles
        int q = tid - 13312;
        int d = q & 3, l = (q >> 2) & 63, kt = q >> 8;
        int g = l >> 4, li = l & 15;
        int s0 = sigma(kt, g, 2 * d), s1 = sigma(kt, g, 2 * d + 1);
        float v0 = (li < 3) ? vw2[s0 * 3 + li] : 0.f;
        float v1 = (li < 3) ? vw2[s1 * 3 + li] : 0.f;
        ((unsigned*)(ws + WS_VA2H))[q] = pack_f16pair(v0, v1);
    }
}

// ---------------- Kernel A: K32-MFMA MLP, LDS frags, 32 px/wave-iter (2 B-sets per ds_read) ----------------
#define A_ITERS 8
__global__ __launch_bounds__(256, 2) void inr_mlp_mfma(
    const float* __restrict__ x, const int* __restrict__ sidx,
    const float* __restrict__ shv, const float* __restrict__ rot,
    const float* __restrict__ cw, const float* __restrict__ cb,
    const float* __restrict__ b2g, const float* __restrict__ b3g,
    const char* __restrict__ ws, float* __restrict__ lr)
{
    __shared__ uint4 sFrag[2816];   // 45056 B: A2 [0..2047], A1 [2048..2559], A3 [2560..2815]
    int tid = threadIdx.x, l = tid & 63, wv = tid >> 6;
    int li = l & 15, g = l >> 4;

    {
        const uint4* wsf = (const uint4*)ws;
        #pragma unroll
        for (int i = 0; i < 11; i++) sFrag[i * 256 + tid] = wsf[i * 256 + tid];
    }

    int base = blockIdx.x * (128 * A_ITERS);   // 1024 px per block
    int img = base >> 16;
    int si = sidx[img];
    float ang = rot[si], sn, cs;
    sincosf(ang, &sn, &cs);
    float shx = shv[2*si], shy = shv[2*si+1];
    bool aff = (si != 0);
    float cw0 = cw[si*3+0], cw1 = cw[si*3+1], cw2 = cw[si*3+2];
    float cb0 = cb[si*3+0], cb1 = cb[si*3+1], cb2 = cb[si*3+2];
    float b30 = b3g[0], b31 = b3g[1], b32 = b3g[2];
    const unsigned ONES = 0x3C003C00u;  // (1.0h, 1.0h)

    __syncthreads();
    const uint4* fp = sFrag + l;    // per-lane frag base; tile i at fp[i*64]

    int pidxA = base + wv * 32 + li;       // set A pixel for this lane's li
    float2 xvA = ((const float2*)x)[pidxA];
    float2 xvB = ((const float2*)x)[pidxA + 16];

    #pragma unroll 1
    for (int it = 0; it < A_ITERS; ++it) {
        float2 xvAn, xvBn;
        if (it < A_ITERS - 1) {
            xvAn = ((const float2*)x)[pidxA + (it + 1) * 128];
            xvBn = ((const float2*)x)[pidxA + 16 + (it + 1) * 128];
        }
        int p0w = base + it * 128 + wv * 32;

        // build B1 frags for both pixel sets
        f16x8 B1A, B1B;
        {
            float cx = fmaf(cs, xvA.x, fmaf(-sn, xvA.y, shx));
            float cy = fmaf(sn, xvA.x, fmaf(cs, xvA.y, shy));
            hf2 ph = __builtin_amdgcn_cvt_pkrtz(cx, cy);
            hf2 pl = __builtin_amdgcn_cvt_pkrtz(cx - (float)ph[0], cy - (float)ph[1]);
            unsigned uh = __builtin_bit_cast(unsigned, ph);
            unsigned ul = __builtin_bit_cast(unsigned, pl);
            uint4 u; u.x = (g == 0) ? uh : 0u; u.y = (g == 0) ? ul : 0u;
            u.z = (g == 0) ? uh : 0u; u.w = (g == 0) ? ONES : 0u;
            B1A = __builtin_bit_cast(f16x8, u);
        }
        {
            float cx = fmaf(cs, xvB.x, fmaf(-sn, xvB.y, shx));
            float cy = fmaf(sn, xvB.x, fmaf(cs, xvB.y, shy));
            hf2 ph = __builtin_amdgcn_cvt_pkrtz(cx, cy);
            hf2 pl = __builtin_amdgcn_cvt_pkrtz(cx - (float)ph[0], cy - (float)ph[1]);
            unsigned uh = __builtin_bit_cast(unsigned, ph);
            unsigned ul = __builtin_bit_cast(unsigned, pl);
            uint4 u; u.x = (g == 0) ? uh : 0u; u.y = (g == 0) ? ul : 0u;
            u.z = (g == 0) ? uh : 0u; u.w = (g == 0) ? ONES : 0u;
            B1B = __builtin_bit_cast(f16x8, u);
        }

        // layer 1: 8 tile-reads, 2 MFMAs each
        uint2 C1A[8], C1B[8];
        #pragma unroll
        for (int t = 0; t < 8; t++) {
            f16x8 a1 = __builtin_bit_cast(f16x8, fp[2048 + t * 64]);
            f32x4 hA = __builtin_amdgcn_mfma_f32_16x16x32_f16(a1, B1A, (f32x4){0.f,0.f,0.f,0.f}, 0, 0, 0);
            f32x4 hB = __builtin_amdgcn_mfma_f32_16x16x32_f16(a1, B1B, (f32x4){0.f,0.f,0.f,0.f}, 0, 0, 0);
            C1A[t].x = cvt_relu(hA[0], hA[1]); C1A[t].y = cvt_relu(hA[2], hA[3]);
            C1B[t].x = cvt_relu(hB[0], hB[1]); C1B[t].y = cvt_relu(hB[2], hB[3]);
        }

        // layer 2: 32 tile-reads, 2 MFMAs each
        uint2 C2A[8], C2B[8];
        #pragma unroll
        for (int t2 = 0; t2 < 8; t2++) {
            f32x4 cA = *(const f32x4*)(b2g + 16 * t2 + g * 4);
            f32x4 cB = cA;
            #pragma unroll
            for (int kt = 0; kt < 4; kt++) {
                f16x8 a2 = __builtin_bit_cast(f16x8, fp[(t2 * 4 + kt) * 64]);
                uint4 buA = {C1A[2*kt].x, C1A[2*kt].y, C1A[2*kt+1].x, C1A[2*kt+1].y};
                uint4 buB = {C1B[2*kt].x, C1B[2*kt].y, C1B[2*kt+1].x, C1B[2*kt+1].y};
                cA = __builtin_amdgcn_mfma_f32_16x16x32_f16(a2, __builtin_bit_cast(f16x8, buA), cA, 0, 0, 0);
                cB = __builtin_amdgcn_mfma_f32_16x16x32_f16(a2, __builtin_bit_cast(f16x8, buB), cB, 0, 0, 0);
            }
            C2A[t2].x = cvt_relu(cA[0], cA[1]); C2A[t2].y = cvt_relu(cA[2], cA[3]);
            C2B[t2].x = cvt_relu(cB[0], cB[1]); C2B[t2].y = cvt_relu(cB[2], cB[3]);
        }

        // layer 3: 4 tile-reads, 2 MFMAs each (single chain per set)
        f32x4 aA = {0.f,0.f,0.f,0.f}, aB = {0.f,0.f,0.f,0.f};
        #pragma unroll
        for (int kt = 0; kt < 4; kt++) {
            f16x8 a3 = __builtin_bit_cast(f16x8, fp[2560 + kt * 64]);
            uint4 buA = {C2A[(2*kt)&7].x, C2A[(2*kt)&7].y, C2A[(2*kt+1)&7].x, C2A[(2*kt+1)&7].y};
            uint4 buB = {C2B[(2*kt)&7].x, C2B[(2*kt)&7].y, C2B[(2*kt+1)&7].x, C2B[(2*kt+1)&7].y};
            aA = __builtin_amdgcn_mfma_f32_16x16x32_f16(a3, __builtin_bit_cast(f16x8, buA), aA, 0, 0, 0);
            aB = __builtin_amdgcn_mfma_f32_16x16x32_f16(a3, __builtin_bit_cast(f16x8, buB), aB, 0, 0, 0);
        }

        if (g == 0) {   // rows 0..2 = channels, col = px = li
            float vA0 = aA[0] + b30, vA1 = aA[1] + b31, vA2 = aA[2] + b32;
            float vB0 = aB[0] + b30, vB1 = aB[1] + b31, vB2 = aB[2] + b32;
            if (aff) {
                vA0 = fmaf(vA0, cw0, cb0); vA1 = fmaf(vA1, cw1, cb1); vA2 = fmaf(vA2, cw2, cb2);
                vB0 = fmaf(vB0, cw0, cb0); vB1 = fmaf(vB1, cw1, cb1); vB2 = fmaf(vB2, cw2, cb2);
            }
            lr[p0w + li] = vA0;               lr[p0w + 16 + li] = vB0;
            lr[NPIX_LR + p0w + li] = vA1;     lr[NPIX_LR + p0w + 16 + li] = vB1;
            lr[2 * NPIX_LR + p0w + li] = vA2; lr[2 * NPIX_LR + p0w + 16 + li] = vB2;
        }
        xvA = xvAn; xvB = xvBn;
    }
}

// ---------------- Kernel B: reg frags + 2-way interleaved j-pairs ----------------
#define B_ITERS 4

struct Taps {
    float2 a0, a1, a2;   // row y0: ch0..2, cols (xa, xa+1)
    float2 b0, b1, b2;   // row y1
    float w00, w01, w10, w11;
};

static __device__ inline Taps issue_taps(const float* __restrict__ lr, int px) {
    Taps t;
    int b = px >> 18, r = px & 262143;
    int oy = r >> 9, ox = r & 511;
    int my = oy >> 1, mx = ox >> 1;
    int y0 = (oy & 1) ? my : my - 1;
    int x0 = (ox & 1) ? mx : mx - 1;
    float wy0 = (oy & 1) ? 0.75f : 0.25f;
    float wx0 = (ox & 1) ? 0.75f : 0.25f;
    int y0c = max(y0, 0), y1c = min(y0 + 1, 255);
    int xa = min(max(x0, 0), 254);
    float wxa = (x0 < 0) ? 1.f : ((x0 > 254) ? 0.f : wx0);
    float wxb = (x0 < 0) ? 0.f : ((x0 > 254) ? 1.f : 1.f - wx0);
    float wy1 = 1.f - wy0;
    t.w00 = wy0 * wxa; t.w01 = wy0 * wxb;
    t.w10 = wy1 * wxa; t.w11 = wy1 * wxb;
    int base = b << 16;
    int o0 = base + y0c * 256 + xa;
    int o1 = base + y1c * 256 + xa;
    t.a0 = *(const float2*)(lr + o0);
    t.a1 = *(const float2*)(lr + NPIX_LR + o0);
    t.a2 = *(const float2*)(lr + 2 * NPIX_LR + o0);
    t.b0 = *(const float2*)(lr + o1);
    t.b1 = *(const float2*)(lr + NPIX_LR + o1);
    t.b2 = *(const float2*)(lr + 2 * NPIX_LR + o1);
    return t;
}

__global__ __launch_bounds__(256, 4) void inr_upsample_var(
    const float* __restrict__ lr, const int* __restrict__ sidx,
    const float* __restrict__ shv, const float* __restrict__ vb2g,
    const char* __restrict__ ws, float* __restrict__ out)
{
    __shared__ uint4 sV[768];   // 12288 B: VA1 [0..511], VA2H [512..767]
    int tid = threadIdx.x, l = tid & 63, wv = tid >> 6;
    int li = l & 15, g = l >> 4;

    {
        const uint4* wsv = (const uint4*)(ws + WS_VA1);
        #pragma unroll
        for (int i = 0; i < 3; i++) sV[i * 256 + tid] = wsv[i * 256 + tid];
    }
    float vb20 = vb2g[0], vb21 = vb2g[1], vb22 = vb2g[2];
    __syncthreads();

    // hoist block-invariant weight frags LDS -> registers (12 x 16B = 48 VGPR)
    f16x8 F1[8], F2[4];
    {
        const uint4* vp = sV + l;
        #pragma unroll
        for (int t = 0; t < 8; t++) F1[t] = __builtin_bit_cast(f16x8, vp[t * 64]);
        #pragma unroll
        for (int t = 0; t < 4; t++) F2[t] = __builtin_bit_cast(f16x8, vp[512 + t * 64]);
    }

    int wbase = (blockIdx.x * 4 + wv) * (64 * B_ITERS);

    #pragma unroll 1
    for (int it = 0; it < B_ITERS; ++it) {
        int pxb = wbase + it * 64;
        int px = pxb + l;
        Taps tp = issue_taps(lr, px);

        float o0 = tp.w00 * tp.a0.x + tp.w01 * tp.a0.y + tp.w10 * tp.b0.x + tp.w11 * tp.b0.y;
        float o1 = tp.w00 * tp.a1.x + tp.w01 * tp.a1.y + tp.w10 * tp.b1.x + tp.w11 * tp.b1.y;
        float o2 = tp.w00 * tp.a2.x + tp.w01 * tp.a2.y + tp.w10 * tp.b2.x + tp.w11 * tp.b2.y;

        {
            float* dst = out + (size_t)px * 3;
            dst[0] = o0; dst[1] = o1; dst[2] = o2;
        }

        // pack P to f16 on the OWNING lane, shfl the packed dwords
        unsigned u1 = pack_f16pair(o0, o1);
        unsigned u2 = pack_f16pair(o2, 1.0f);

        #pragma unroll
        for (int jp = 0; jp < 2; jp++) {
            int j0 = jp * 2, j1 = jp * 2 + 1;
            // issue both shfl pairs up front (independent)
            unsigned sA0 = (unsigned)__shfl((int)u1, j0 * 16 + li, 64);
            unsigned sB0 = (unsigned)__shfl((int)u2, j0 * 16 + li, 64);
            unsigned sA1 = (unsigned)__shfl((int)u1, j1 * 16 + li, 64);
            unsigned sB1 = (unsigned)__shfl((int)u2, j1 * 16 + li, 64);
            uint4 bq0, bq1;
            bq0.x = (g == 0) ? sA0 : 0u; bq0.y = (g == 0) ? sB0 : 0u; bq0.z = 0u; bq0.w = 0u;
            bq1.x = (g == 0) ? sA1 : 0u; bq1.y = (g == 0) ? sB1 : 0u; bq1.z = 0u; bq1.w = 0u;
            f16x8 Ba = __builtin_bit_cast(f16x8, bq0);
            f16x8 Bb = __builtin_bit_cast(f16x8, bq1);

            // v1: 16 MFMAs, two independent streams interleaved
            uint2 C1a[8], C1b[8];
            #pragma unroll
            for (int t = 0; t < 8; t++) {
                f32x4 va = __builtin_amdgcn_mfma_f32_16x16x32_f16(F1[t], Ba, (f32x4){0.f,0.f,0.f,0.f}, 0, 0, 0);
                f32x4 vb = __builtin_amdgcn_mfma_f32_16x16x32_f16(F1[t], Bb, (f32x4){0.f,0.f,0.f,0.f}, 0, 0, 0);
                C1a[t].x = cvt_relu(va[0], va[1]); C1a[t].y = cvt_relu(va[2], va[3]);
                C1b[t].x = cvt_relu(vb[0], vb[1]); C1b[t].y = cvt_relu(vb[2], vb[3]);
            }

            // v2: 8 MFMAs, two independent chains
            f32x4 acca = {0.f,0.f,0.f,0.f}, accb = {0.f,0.f,0.f,0.f};
            #pragma unroll
            for (int kt = 0; kt < 4; kt++) {
                uint4 bua = {C1a[2*kt].x, C1a[2*kt].y, C1a[2*kt+1].x, C1a[2*kt+1].y};
                uint4 bub = {C1b[2*kt].x, C1b[2*kt].y, C1b[2*kt+1].x, C1b[2*kt+1].y};
                acca = __builtin_amdgcn_mfma_f32_16x16x32_f16(F2[kt], __builtin_bit_cast(f16x8, bua), acca, 0, 0, 0);
                accb = __builtin_amdgcn_mfma_f32_16x16x32_f16(F2[kt], __builtin_bit_cast(f16x8, bub), accb, 0, 0, 0);
            }

            if (g == 0) {   // rows 0..2 = channels, col = px = li
                float* var0 = out + OUT_OFF_VAR + (size_t)(pxb + j0 * 16 + li) * 3;
                var0[0] = __expf(acca[0] + vb20);
                var0[1] = __expf(acca[1] + vb21);
                var0[2] = __expf(acca[2] + vb22);
                float* var1 = out + OUT_OFF_VAR + (size_t)(pxb + j1 * 16 + li) * 3;
                var1[0] = __expf(accb[0] + vb20);
                var1[1] = __expf(accb[1] + vb21);
                var1[2] = __expf(accb[2] + vb22);
            }
        }
    }

    if (blockIdx.x == 0 && tid < 16) {
        out[OUT_OFF_DX + tid] = shv[2 * sidx[tid & 7] + (tid >> 3)];
    }
}

extern "C" void kernel_launch(void* const* d_in, const int* in_sizes, int n_in,
                              void* d_out, int out_size, void* d_ws, size_t ws_size,
                              hipStream_t stream)
{
    const float* x    = (const float*)d_in[0];
    const int*   sidx = (const int*)d_in[1];
    const float* shv  = (const float*)d_in[3];
    const float* rot  = (const float*)d_in[4];
    const float* cwp  = (const float*)d_in[5];
    const float* cbp  = (const float*)d_in[6];
    const float* w1   = (const float*)d_in[7];
    const float* b1   = (const float*)d_in[8];
    const float* w2   = (const float*)d_in[9];
    const float* b2   = (const float*)d_in[10];
    const float* w3   = (const float*)d_in[11];
    const float* b3   = (const float*)d_in[12];
    const float* vw1  = (const float*)d_in[13];
    const float* vb1  = (const float*)d_in[14];
    const float* vw2  = (const float*)d_in[15];
    const float* vb2  = (const float*)d_in[16];

    char* ws = (char*)d_ws;
    float* lr = (float*)(ws + WS_LR);

    inr_prep<<<56, 256, 0, stream>>>(w1, b1, w2, w3, vw1, vb1, vw2, ws);
    inr_mlp_mfma<<<NPIX_LR / (128 * A_ITERS), 256, 0, stream>>>(x, sidx, shv, rot, cwp, cbp, b2, b3, ws, lr);
    inr_upsample_var<<<NPIX_HR / (256 * B_ITERS), 256, 0, stream>>>(lr, sidx, shv, vb2, ws, (float*)d_out);
}